// Round 8
// baseline (124.496 us; speedup 1.0000x reference)
//
#include <hip/hip_runtime.h>

// knnLoss: B=4, downsample 400x400 stride-4 -> 10000 pts x 3ch, NN sq-dist mean.
// d2(t,s) = tt + (ss - 2 t.s); min over the paren term, add tt at the end.
// Sources pre-transformed to (-2x,-2y,-2z,ss).
//
// KEY (R7 post-mortem): v_pk_fma_f32 is 4 cyc on the FP32 pipe (spec 157 TF
// caps it) -> packing never helps. Floor = 3 fma + 0.5 min3 = 7 cyc/pair
// ~ 19 us. All prior variants added a 16-32 us LDS-broadcast tax on top.
// This version has NO LDS AT ALL: source chunks live in a padded per-chunk
// global layout and are read with block-uniform addresses -> scalar (SMEM)
// loads into SGPRs; v_fma_f32 takes the source component as its one legal
// SGPR operand. Targets/mins in VGPRs. No barriers.
// Grid: (TBLKS=5, NC=64, B=4) = 1280 blocks x 256 = exactly 5 blocks/CU.

#define BATCH  4
#define NPTS   10000
#define NPAD   10240      // padded target count per batch
#define H      400
#define W      400
#define STRIDE 4
#define OUTW   100
#define NC     64         // source chunks
#define CHUNK  157        // ceil(NPTS/NC)
#define CPAD   160        // padded chunk slot (multiple of 4, sentinel-filled)
#define BLOCK  256
#define TPT    8          // targets per thread
#define TBLKS  5          // NPAD / (BLOCK*TPT)
#define RBLOCK 256

__device__ __forceinline__ float min3f(float a, float b, float c) {
    float r;
    asm("v_min3_f32 %0, %1, %2, %3" : "=v"(r) : "v"(a), "v"(b), "v"(c));
    return r;
}

// ---------------------------------------------------------------- kernel 1
// Targets -> T4[b*NPAD+n] = (x,y,z,tt), zero-padded.
// Sources -> padded chunk layout S4[(b*NC+c)*CPAD + i] = (-2x,-2y,-2z,ss),
// sentinel (0,0,0,+big) outside the valid range so knn needs no bounds logic.
__global__ void prep_kernel(const float* __restrict__ tgt,
                            const float* __restrict__ src,
                            float4* __restrict__ S4,
                            float4* __restrict__ T4) {
    int gid = blockIdx.x * blockDim.x + threadIdx.x;
    if (gid < BATCH * NPAD) {
        int b = gid / NPAD;
        int n = gid % NPAD;
        float4 v = make_float4(0.f, 0.f, 0.f, 0.f);
        if (n < NPTS) {
            int h = n / OUTW, w = n % OUTW;
            int base = ((b * 3) * H + h * STRIDE) * W + w * STRIDE;
            float x = tgt[base];
            float y = tgt[base + H * W];
            float z = tgt[base + 2 * H * W];
            v = make_float4(x, y, z, x * x + y * y + z * z);
        }
        T4[gid] = v;
    } else {
        int sid = gid - BATCH * NPAD;
        if (sid < BATCH * NC * CPAD) {
            int b = sid / (NC * CPAD);
            int r = sid % (NC * CPAD);
            int c = r / CPAD;
            int i = r % CPAD;
            int m = c * CHUNK + i;            // global source index
            float4 v = make_float4(0.f, 0.f, 0.f, 3.0e38f);
            if (i < CHUNK && m < NPTS) {
                int h = m / OUTW, w = m % OUTW;
                int base = ((b * 3) * H + h * STRIDE) * W + w * STRIDE;
                float x = src[base];
                float y = src[base + H * W];
                float z = src[base + 2 * H * W];
                v = make_float4(-2.f * x, -2.f * y, -2.f * z,
                                x * x + y * y + z * z);
            }
            S4[sid] = v;
        }
    }
}

// ---------------------------------------------------------------- kernel 2
// block = (tblk, cblk, b): 2048 targets x one 160-slot source chunk.
// Source reads are block-uniform -> SMEM path; zero LDS, zero barriers.
__global__ __launch_bounds__(BLOCK) void knn_kernel(
        const float4* __restrict__ S4,
        const float4* __restrict__ T4,
        float* __restrict__ M2) {
    const int tblk = blockIdx.x;  // 0..TBLKS-1
    const int cblk = blockIdx.y;  // 0..NC-1
    const int b    = blockIdx.z;  // 0..BATCH-1
    const int tid  = threadIdx.x;

    const float4* sbase = S4 + (size_t)(b * NC + cblk) * CPAD;  // uniform

    const int tbase = b * NPAD + tblk * (BLOCK * TPT) + tid;
    float tx[TPT], ty[TPT], tz[TPT], mn[TPT];
#pragma unroll
    for (int k = 0; k < TPT; k++) {
        float4 t = T4[tbase + k * BLOCK];
        tx[k] = t.x; ty[k] = t.y; tz[k] = t.z;
        mn[k] = 3.0e38f;
    }

    // 4 sources per iteration; all addresses uniform (s_load + lgkmcnt
    // scheduling by the compiler), 2 min3 folds per target.
    for (int j = 0; j < CPAD; j += 4) {
        float4 sa = sbase[j + 0];
        float4 sb = sbase[j + 1];
        float4 sc = sbase[j + 2];
        float4 sd = sbase[j + 3];
#pragma unroll
        for (int k = 0; k < TPT; k++) {
            float da = fmaf(tx[k], sa.x, sa.w);
            da = fmaf(ty[k], sa.y, da);
            da = fmaf(tz[k], sa.z, da);
            float db = fmaf(tx[k], sb.x, sb.w);
            db = fmaf(ty[k], sb.y, db);
            db = fmaf(tz[k], sb.z, db);
            float dc = fmaf(tx[k], sc.x, sc.w);
            dc = fmaf(ty[k], sc.y, dc);
            dc = fmaf(tz[k], sc.z, dc);
            float dd = fmaf(tx[k], sd.x, sd.w);
            dd = fmaf(ty[k], sd.y, dd);
            dd = fmaf(tz[k], sd.z, dd);
            mn[k] = min3f(mn[k], da, db);
            mn[k] = min3f(mn[k], dc, dd);
        }
    }

    float* obase = M2 + (size_t)(cblk * BATCH + b) * NPAD
                      + tblk * (BLOCK * TPT) + tid;
#pragma unroll
    for (int k = 0; k < TPT; k++) obase[k * BLOCK] = mn[k];
}

// ---------------------------------------------------------------- kernel 3
__global__ void reduce_kernel(const float* __restrict__ M2,
                              const float4* __restrict__ T4,
                              float* __restrict__ out) {
    __shared__ float red[RBLOCK / 64];
    int gid = blockIdx.x * RBLOCK + threadIdx.x;
    float val = 0.f;
    if (gid < BATCH * NPTS) {
        int b = gid / NPTS;
        int n = gid % NPTS;
        float m = 3.0e38f;
#pragma unroll 8
        for (int c = 0; c < NC; c++)
            m = fminf(m, M2[(size_t)(c * BATCH + b) * NPAD + n]);
        float tt = T4[b * NPAD + n].w;
        val = fmaxf(m + tt, 0.f);
    }
#pragma unroll
    for (int off = 32; off > 0; off >>= 1)
        val += __shfl_down(val, off, 64);
    int lane = threadIdx.x & 63;
    int wave = threadIdx.x >> 6;
    if (lane == 0) red[wave] = val;
    __syncthreads();
    if (threadIdx.x == 0) {
        float s = 0.f;
        for (int wv = 0; wv < RBLOCK / 64; wv++) s += red[wv];
        atomicAdd(out, s * (1.0f / (BATCH * NPTS * 3)));
    }
}

extern "C" void kernel_launch(void* const* d_in, const int* in_sizes, int n_in,
                              void* d_out, int out_size, void* d_ws, size_t ws_size,
                              hipStream_t stream) {
    const float* tgt = (const float*)d_in[0];   // target_pc (4,3,400,400)
    const float* src = (const float*)d_in[1];   // source_pc (4,3,400,400)
    float* out = (float*)d_out;

    char* ws = (char*)d_ws;
    float4* S4 = (float4*)ws;                                    // B*NC*CPAD float4
    float4* T4 = (float4*)(ws + (size_t)BATCH * NC * CPAD * 16); // B*NPAD float4
    float*  M2 = (float*)(ws + (size_t)BATCH * NC * CPAD * 16
                             + (size_t)BATCH * NPAD * 16);       // NC*B*NPAD floats

    hipMemsetAsync(out, 0, sizeof(float), stream);

    int nprep = BATCH * NPAD + BATCH * NC * CPAD;
    prep_kernel<<<(nprep + RBLOCK - 1) / RBLOCK, RBLOCK, 0, stream>>>(tgt, src, S4, T4);

    knn_kernel<<<dim3(TBLKS, NC, BATCH), BLOCK, 0, stream>>>(S4, T4, M2);

    reduce_kernel<<<(BATCH * NPTS + RBLOCK - 1) / RBLOCK, RBLOCK, 0, stream>>>(
        M2, T4, out);
}

// Round 9
// 122.216 us; speedup vs baseline: 1.0187x; 1.0187x over previous
//
#include <hip/hip_runtime.h>

// knnLoss: B=4, downsample 400x400 stride-4 -> 10000 pts x 3ch, NN sq-dist mean.
// d2(t,s) = tt + (ss - 2 t.s); min over the paren term, add tt at the end.
// Sources pre-transformed to (-2x,-2y,-2z,ss).
//
// R8 post-mortem: compiler never picks SMEM for uniform loads. This version
// FORCES the scalar path: s_load_dwordx16 inline asm -> sources live in
// SGPRs (v_fma_f32's one legal SGPR operand), double-buffered A/B with
// explicit s_waitcnt carrying "+s" deps. K-loop has ZERO LDS and ZERO VMEM:
// just 2 s_load + 1 waitcnt + 224 VALU per 8-source group. VALU floor
// = 4.19e8 pairs * 3.5 instr / 64 * 2cyc / 1024 SIMD = 19.1 us.
// Grid: (TBLKS=5, NC=64, B=4) = 1280 blocks x 256 = exactly 5 blocks/CU.

#define BATCH  4
#define NPTS   10000
#define NPAD   10240      // padded target count per batch
#define H      400
#define W      400
#define STRIDE 4
#define OUTW   100
#define NC     64         // source chunks
#define CHUNK  157        // ceil(NPTS/NC)
#define CPAD   160        // padded chunk slot (multiple of 8, sentinel-filled)
#define NG     (CPAD / 8) // 8-source groups per chunk = 20 (even)
#define BLOCK  256
#define TPT    8          // targets per thread
#define TBLKS  5          // NPAD / (BLOCK*TPT)
#define RBLOCK 256

typedef float sv16 __attribute__((ext_vector_type(16)));

__device__ __forceinline__ float min3f(float a, float b, float c) {
    float r;
    asm("v_min3_f32 %0, %1, %2, %3" : "=v"(r) : "v"(a), "v"(b), "v"(c));
    return r;
}

// ---------------------------------------------------------------- kernel 1
// Targets -> T4[b*NPAD+n] = (x,y,z,tt), zero-padded.
// Sources -> padded chunk layout S4[(b*NC+c)*CPAD + i] = (-2x,-2y,-2z,ss),
// sentinel (0,0,0,+big) outside valid range so knn needs no bounds logic.
__global__ void prep_kernel(const float* __restrict__ tgt,
                            const float* __restrict__ src,
                            float4* __restrict__ S4,
                            float4* __restrict__ T4) {
    int gid = blockIdx.x * blockDim.x + threadIdx.x;
    if (gid < BATCH * NPAD) {
        int b = gid / NPAD;
        int n = gid % NPAD;
        float4 v = make_float4(0.f, 0.f, 0.f, 0.f);
        if (n < NPTS) {
            int h = n / OUTW, w = n % OUTW;
            int base = ((b * 3) * H + h * STRIDE) * W + w * STRIDE;
            float x = tgt[base];
            float y = tgt[base + H * W];
            float z = tgt[base + 2 * H * W];
            v = make_float4(x, y, z, x * x + y * y + z * z);
        }
        T4[gid] = v;
    } else {
        int sid = gid - BATCH * NPAD;
        if (sid < BATCH * NC * CPAD) {
            int b = sid / (NC * CPAD);
            int r = sid % (NC * CPAD);
            int c = r / CPAD;
            int i = r % CPAD;
            int m = c * CHUNK + i;            // global source index
            float4 v = make_float4(0.f, 0.f, 0.f, 3.0e38f);
            if (i < CHUNK && m < NPTS) {
                int h = m / OUTW, w = m % OUTW;
                int base = ((b * 3) * H + h * STRIDE) * W + w * STRIDE;
                float x = src[base];
                float y = src[base + H * W];
                float z = src[base + 2 * H * W];
                v = make_float4(-2.f * x, -2.f * y, -2.f * z,
                                x * x + y * y + z * z);
            }
            S4[sid] = v;
        }
    }
}

// ---------------------------------------------------------------- kernel 2
// One sv16 = 4 sources. Per quad per target: 3 fma + (folded) min3.
#define QUAD(cv)                                                            \
    _Pragma("unroll")                                                       \
    for (int k = 0; k < TPT; k++) {                                         \
        float da = fmaf(tx[k], cv[0], cv[3]);                               \
        da = fmaf(ty[k], cv[1], da);                                        \
        da = fmaf(tz[k], cv[2], da);                                        \
        float db = fmaf(tx[k], cv[4], cv[7]);                               \
        db = fmaf(ty[k], cv[5], db);                                        \
        db = fmaf(tz[k], cv[6], db);                                        \
        float dc = fmaf(tx[k], cv[8], cv[11]);                              \
        dc = fmaf(ty[k], cv[9], dc);                                        \
        dc = fmaf(tz[k], cv[10], dc);                                       \
        float dd = fmaf(tx[k], cv[12], cv[15]);                             \
        dd = fmaf(ty[k], cv[13], dd);                                       \
        dd = fmaf(tz[k], cv[14], dd);                                       \
        mn[k] = min3f(mn[k], da, db);                                       \
        mn[k] = min3f(mn[k], dc, dd);                                       \
    }

#define SLOAD(dst, addr)                                                    \
    asm volatile("s_load_dwordx16 %0, %1, 0x0"                              \
                 : "=s"(dst) : "s"((const void*)(addr)))

#define SWAIT2(r0, r1)                                                      \
    asm volatile("s_waitcnt lgkmcnt(0)" : "+s"(r0), "+s"(r1))

__global__ __launch_bounds__(BLOCK) void knn_kernel(
        const float4* __restrict__ S4,
        const float4* __restrict__ T4,
        float* __restrict__ M2) {
    const int tblk = blockIdx.x;  // 0..TBLKS-1
    const int cblk = blockIdx.y;  // 0..NC-1
    const int b    = blockIdx.z;  // 0..BATCH-1
    const int tid  = threadIdx.x;

    const float4* sbase = S4 + (size_t)(b * NC + cblk) * CPAD;  // uniform

    const int tbase = b * NPAD + tblk * (BLOCK * TPT) + tid;
    float tx[TPT], ty[TPT], tz[TPT], mn[TPT];
#pragma unroll
    for (int k = 0; k < TPT; k++) {
        float4 t = T4[tbase + k * BLOCK];
        tx[k] = t.x; ty[k] = t.y; tz[k] = t.z;
        mn[k] = 3.0e38f;
    }

    // Double-buffered scalar prefetch: group = 8 sources = 2 x s_load_dwordx16.
    sv16 a0, a1, b0, b1;
    SLOAD(a0, sbase);            // group 0
    SLOAD(a1, sbase + 4);
#pragma unroll
    for (int g = 0; g < NG; g += 2) {
        SWAIT2(a0, a1);
        if (g + 1 < NG) {
            SLOAD(b0, sbase + 8 * (g + 1));
            SLOAD(b1, sbase + 8 * (g + 1) + 4);
        }
        QUAD(a0)
        QUAD(a1)
        if (g + 1 < NG) {
            SWAIT2(b0, b1);
            if (g + 2 < NG) {
                SLOAD(a0, sbase + 8 * (g + 2));
                SLOAD(a1, sbase + 8 * (g + 2) + 4);
            }
            QUAD(b0)
            QUAD(b1)
        }
    }

    float* obase = M2 + (size_t)(cblk * BATCH + b) * NPAD
                      + tblk * (BLOCK * TPT) + tid;
#pragma unroll
    for (int k = 0; k < TPT; k++) obase[k * BLOCK] = mn[k];
}

// ---------------------------------------------------------------- kernel 3
__global__ void reduce_kernel(const float* __restrict__ M2,
                              const float4* __restrict__ T4,
                              float* __restrict__ out) {
    __shared__ float red[RBLOCK / 64];
    int gid = blockIdx.x * RBLOCK + threadIdx.x;
    float val = 0.f;
    if (gid < BATCH * NPTS) {
        int b = gid / NPTS;
        int n = gid % NPTS;
        float m = 3.0e38f;
#pragma unroll 8
        for (int c = 0; c < NC; c++)
            m = fminf(m, M2[(size_t)(c * BATCH + b) * NPAD + n]);
        float tt = T4[b * NPAD + n].w;
        val = fmaxf(m + tt, 0.f);
    }
#pragma unroll
    for (int off = 32; off > 0; off >>= 1)
        val += __shfl_down(val, off, 64);
    int lane = threadIdx.x & 63;
    int wave = threadIdx.x >> 6;
    if (lane == 0) red[wave] = val;
    __syncthreads();
    if (threadIdx.x == 0) {
        float s = 0.f;
        for (int wv = 0; wv < RBLOCK / 64; wv++) s += red[wv];
        atomicAdd(out, s * (1.0f / (BATCH * NPTS * 3)));
    }
}

extern "C" void kernel_launch(void* const* d_in, const int* in_sizes, int n_in,
                              void* d_out, int out_size, void* d_ws, size_t ws_size,
                              hipStream_t stream) {
    const float* tgt = (const float*)d_in[0];   // target_pc (4,3,400,400)
    const float* src = (const float*)d_in[1];   // source_pc (4,3,400,400)
    float* out = (float*)d_out;

    char* ws = (char*)d_ws;
    float4* S4 = (float4*)ws;                                    // B*NC*CPAD float4
    float4* T4 = (float4*)(ws + (size_t)BATCH * NC * CPAD * 16); // B*NPAD float4
    float*  M2 = (float*)(ws + (size_t)BATCH * NC * CPAD * 16
                             + (size_t)BATCH * NPAD * 16);       // NC*B*NPAD floats

    hipMemsetAsync(out, 0, sizeof(float), stream);

    int nprep = BATCH * NPAD + BATCH * NC * CPAD;
    prep_kernel<<<(nprep + RBLOCK - 1) / RBLOCK, RBLOCK, 0, stream>>>(tgt, src, S4, T4);

    knn_kernel<<<dim3(TBLKS, NC, BATCH), BLOCK, 0, stream>>>(S4, T4, M2);

    reduce_kernel<<<(BATCH * NPTS + RBLOCK - 1) / RBLOCK, RBLOCK, 0, stream>>>(
        M2, T4, out);
}

// Round 10
// 117.074 us; speedup vs baseline: 1.0634x; 1.0439x over previous
//
#include <hip/hip_runtime.h>
#include <hip/hip_bf16.h>

// knnLoss: B=4, downsample 400x400 stride-4 -> 10000 pts x 3, NN sq-dist mean.
//
// R9 post-mortem: scalar-pipe formulations are stuck at 35-52us (compiler
// re-rolls every unrolled structure; VALU issue floor 19us never reached).
// This version moves the pair computation onto the MFMA pipe with a bf16
// hi/lo split GEMM: per pair, one K=11 dot computes
//   d = t.(-2s) + ss  via  A=[th*3, th*3, tl*3, 1, 1], B=[vh*3, vl*3, vh*3,
//   ssh, ssl]   (v=-2s; hi/lo bf16 splits; products exact in fp32)
// error ~2^-15 per distance; final scalar is a mean over 40k points -> ~1e-6.
// One v_mfma_f32_32x32x16_bf16 = 1024 pairs (8cyc) + 16 v_min epilogue.
// C/D layout (measured m74/m101): col=lane&31 (=source), row=(reg&3)+8*(reg>>2)
// +4*(lane>>5) (=target). Running min per acc reg = min over sources; final
// cross-lane shfl_xor min over the 32 column-lanes.
// Grid: (80 row-blocks x NCH=4 col-chunks x 4 batches) = 1280 blocks x 256
// = exactly 5 blocks/CU; 4 independent waves/block; NO LDS, NO barriers.

#define BATCH  4
#define NPTS   10000
#define NPAD   10240
#define H      400
#define W      400
#define STRIDE 4
#define OUTW   100
#define NCH    4          // column chunks
#define CCOLS  (NPAD / NCH)     // 2560 cols per chunk
#define CTILES (CCOLS / 32)     // 80 col-tiles per chunk
#define MT     128        // rows per block (4 waves x 32)
#define RBLOCK 256

typedef short short8 __attribute__((ext_vector_type(8)));
typedef float f32x16 __attribute__((ext_vector_type(16)));

__device__ __forceinline__ unsigned short f2bf(float x) {
    __hip_bfloat16 h = __float2bfloat16(x);
    return *reinterpret_cast<unsigned short*>(&h);
}
__device__ __forceinline__ float bf2f(unsigned short u) {
    __hip_bfloat16 h = *reinterpret_cast<__hip_bfloat16*>(&u);
    return __bfloat162float(h);
}

// ---------------------------------------------------------------- kernel 1
// first B*NPAD gids: targets -> T4 (x,y,z,tt) + A_pack row (16 bf16)
// next  B*NPAD gids: sources -> B_pack row (16 bf16); sentinel past NPTS.
__global__ void prep_kernel(const float* __restrict__ tgt,
                            const float* __restrict__ src,
                            unsigned short* __restrict__ A_pack,
                            unsigned short* __restrict__ B_pack,
                            float4* __restrict__ T4) {
    int gid = blockIdx.x * blockDim.x + threadIdx.x;
    if (gid < BATCH * NPAD) {
        int b = gid / NPAD, n = gid % NPAD;
        unsigned short a[16];
#pragma unroll
        for (int i = 0; i < 16; i++) a[i] = 0;
        float4 tv = make_float4(0.f, 0.f, 0.f, 0.f);
        if (n < NPTS) {
            int h = n / OUTW, w = n % OUTW;
            int base = ((b * 3) * H + h * STRIDE) * W + w * STRIDE;
            float x = tgt[base];
            float y = tgt[base + H * W];
            float z = tgt[base + 2 * H * W];
            tv = make_float4(x, y, z, x * x + y * y + z * z);
            unsigned short th0 = f2bf(x), th1 = f2bf(y), th2 = f2bf(z);
            a[0] = th0; a[1] = th1; a[2] = th2;
            a[3] = th0; a[4] = th1; a[5] = th2;
            a[6] = f2bf(x - bf2f(th0));
            a[7] = f2bf(y - bf2f(th1));
            a[8] = f2bf(z - bf2f(th2));
            a[9] = f2bf(1.0f); a[10] = f2bf(1.0f);
        }
        T4[gid] = tv;
        uint4* dst = (uint4*)(A_pack + (size_t)gid * 16);
        dst[0] = *(uint4*)&a[0];
        dst[1] = *(uint4*)&a[8];
    } else {
        int sid = gid - BATCH * NPAD;
        if (sid < BATCH * NPAD) {
            int b = sid / NPAD, n = sid % NPAD;
            unsigned short v[16];
#pragma unroll
            for (int i = 0; i < 16; i++) v[i] = 0;
            if (n < NPTS) {
                int h = n / OUTW, w = n % OUTW;
                int base = ((b * 3) * H + h * STRIDE) * W + w * STRIDE;
                float x = src[base];
                float y = src[base + H * W];
                float z = src[base + 2 * H * W];
                float ss = x * x + y * y + z * z;
                float v0 = -2.f * x, v1 = -2.f * y, v2 = -2.f * z;
                unsigned short vh0 = f2bf(v0), vh1 = f2bf(v1), vh2 = f2bf(v2);
                v[0] = vh0; v[1] = vh1; v[2] = vh2;
                v[3] = f2bf(v0 - bf2f(vh0));
                v[4] = f2bf(v1 - bf2f(vh1));
                v[5] = f2bf(v2 - bf2f(vh2));
                v[6] = vh0; v[7] = vh1; v[8] = vh2;
                unsigned short sh = f2bf(ss);
                v[9] = sh; v[10] = f2bf(ss - bf2f(sh));
            } else {
                v[9] = f2bf(1.0e30f);   // sentinel: dot = 1e30, never the min
            }
            uint4* dst = (uint4*)(B_pack + (size_t)sid * 16);
            dst[0] = *(uint4*)&v[0];
            dst[1] = *(uint4*)&v[8];
        }
    }
}

// ---------------------------------------------------------------- kernel 2
// block = (rowblk, cchunk, b); 4 waves, each: 32 rows x 2560-col sweep.
__global__ __launch_bounds__(RBLOCK) void knn_kernel(
        const unsigned short* __restrict__ A_pack,
        const unsigned short* __restrict__ B_pack,
        float* __restrict__ M2) {
    const int wave = threadIdx.x >> 6;
    const int lane = threadIdx.x & 63;
    const int l31  = lane & 31;
    const int half = lane >> 5;
    const int b      = blockIdx.z;
    const int cchunk = blockIdx.y;
    const int r0     = blockIdx.x * MT + wave * 32;   // global row base

    // A fragment: row = r0 + l31, k-slots = half*8 .. +7
    union { uint4 u; short8 s; } af, bf, bn;
    af.u = *(const uint4*)(A_pack + ((size_t)b * NPAD + r0 + l31) * 16 + half * 8);

    const unsigned short* bbase =
        B_pack + ((size_t)b * NPAD + (size_t)cchunk * CCOLS + l31) * 16 + half * 8;

    float rmin[16];
#pragma unroll
    for (int r = 0; r < 16; r++) rmin[r] = 3.0e38f;

    bf.u = *(const uint4*)bbase;
    for (int ct = 0; ct < CTILES; ct++) {
        if (ct + 1 < CTILES)
            bn.u = *(const uint4*)(bbase + (size_t)(ct + 1) * 32 * 16);
        f32x16 z = {};
        f32x16 acc = __builtin_amdgcn_mfma_f32_32x32x16_bf16(af.s, bf.s, z, 0, 0, 0);
#pragma unroll
        for (int r = 0; r < 16; r++) rmin[r] = fminf(rmin[r], acc[r]);
        bf.u = bn.u;
    }

    // cross-lane min over the 32 column-lanes (xor masks stay in the half)
#pragma unroll
    for (int r = 0; r < 16; r++) {
        float v = rmin[r];
        v = fminf(v, __shfl_xor(v, 1, 64));
        v = fminf(v, __shfl_xor(v, 2, 64));
        v = fminf(v, __shfl_xor(v, 4, 64));
        v = fminf(v, __shfl_xor(v, 8, 64));
        v = fminf(v, __shfl_xor(v, 16, 64));
        rmin[r] = v;
    }
    if (l31 == 0) {
        float* o = M2 + ((size_t)cchunk * BATCH + b) * NPAD + r0;
#pragma unroll
        for (int r = 0; r < 16; r++) {
            int row = (r & 3) + 8 * (r >> 2) + 4 * half;
            o[row] = rmin[r];
        }
    }
}

// ---------------------------------------------------------------- kernel 3
__global__ void reduce_kernel(const float* __restrict__ M2,
                              const float4* __restrict__ T4,
                              float* __restrict__ out) {
    __shared__ float red[RBLOCK / 64];
    int gid = blockIdx.x * RBLOCK + threadIdx.x;
    float val = 0.f;
    if (gid < BATCH * NPTS) {
        int b = gid / NPTS;
        int n = gid % NPTS;
        float m = 3.0e38f;
#pragma unroll
        for (int c = 0; c < NCH; c++)
            m = fminf(m, M2[((size_t)c * BATCH + b) * NPAD + n]);
        float tt = T4[b * NPAD + n].w;
        val = fmaxf(m + tt, 0.f);
    }
#pragma unroll
    for (int off = 32; off > 0; off >>= 1)
        val += __shfl_down(val, off, 64);
    int lane = threadIdx.x & 63;
    int wave = threadIdx.x >> 6;
    if (lane == 0) red[wave] = val;
    __syncthreads();
    if (threadIdx.x == 0) {
        float s = 0.f;
        for (int wv = 0; wv < RBLOCK / 64; wv++) s += red[wv];
        atomicAdd(out, s * (1.0f / (BATCH * NPTS * 3)));
    }
}

extern "C" void kernel_launch(void* const* d_in, const int* in_sizes, int n_in,
                              void* d_out, int out_size, void* d_ws, size_t ws_size,
                              hipStream_t stream) {
    const float* tgt = (const float*)d_in[0];   // target_pc (4,3,400,400)
    const float* src = (const float*)d_in[1];   // source_pc (4,3,400,400)
    float* out = (float*)d_out;

    char* ws = (char*)d_ws;
    unsigned short* A_pack = (unsigned short*)ws;                 // B*NPAD*16 u16
    unsigned short* B_pack = (unsigned short*)(ws + (size_t)BATCH * NPAD * 32);
    float4* T4 = (float4*)(ws + (size_t)BATCH * NPAD * 64);       // B*NPAD f4
    float*  M2 = (float*)(ws + (size_t)BATCH * NPAD * 64
                             + (size_t)BATCH * NPAD * 16);        // NCH*B*NPAD f

    hipMemsetAsync(out, 0, sizeof(float), stream);

    int nprep = 2 * BATCH * NPAD;
    prep_kernel<<<(nprep + RBLOCK - 1) / RBLOCK, RBLOCK, 0, stream>>>(
        tgt, src, A_pack, B_pack, T4);

    knn_kernel<<<dim3(NPAD / MT, NCH, BATCH), RBLOCK, 0, stream>>>(
        A_pack, B_pack, M2);

    reduce_kernel<<<(BATCH * NPTS + RBLOCK - 1) / RBLOCK, RBLOCK, 0, stream>>>(
        M2, T4, out);
}